// Round 5
// baseline (1456.812 us; speedup 1.0000x reference)
//
#include <hip/hip_runtime.h>
#include <cstdint>
#include <cstddef>

typedef _Float16 f16;
typedef _Float16 f16x8 __attribute__((ext_vector_type(8)));
typedef _Float16 f16x4 __attribute__((ext_vector_type(4)));
typedef _Float16 f16x2 __attribute__((ext_vector_type(2)));
typedef float f32x4 __attribute__((ext_vector_type(4)));

#define MFMA16(a, b, c) __builtin_amdgcn_mfma_f32_16x16x32_f16((a), (b), (c), 0, 0, 0)

// sched_group_barrier masks (LLVM SchedGroupMask, verified m137)
#define SGB(mask, n) __builtin_amdgcn_sched_group_barrier((mask), (n), 0)
#define SG_VALU 0x2
#define SG_MFMA 0x8
#define SG_VMEM_RD 0x20
#define SG_VMEM_WR 0x40
#define SG_DS_RD 0x100
#define SG_DS_WR 0x200

// Problem sizes: B=64, S=1024, D=128, H=256, 2H=512

// Workspace layout (bytes). Total ~194.8 MiB.
static constexpr size_t UT_OFF  = 0;                         // Ut  [2dir][2gate][256cc][256k] f16 = 524288
static constexpr size_t WT_OFF  = 524288;                    // Wt  [2dir][512cc2][128k] f16   = 262144
static constexpr size_t W1T_OFF = 786432;                    // W1t [512n][512k] f16           = 524288
static constexpr size_t XP_OFF  = 1310720;                   // xp2 [2dir*4g][1024s][8192] f16 = 134217728
static constexpr size_t OUT_OFF = XP_OFF + 134217728;        // out16 [64b][1024s][512] f16    = 67108864
static constexpr size_t SC_OFF  = OUT_OFF + 67108864;        // scores [64][1024] f32          = 262144
static constexpr size_t AT_OFF  = SC_OFF + 262144;           // attn   [64][1024] f32          = 262144
static constexpr size_t PART_OFF= AT_OFF + 262144;           // partials [64][8][512] f32      = 1048576

// log2(e) folded into z-path, 2*log2(e) into h-path so the recurrence uses raw
// v_exp_f32 (2^x) with no per-element scale mul.
#define SCALE_Z 1.4426950408889634f
#define SCALE_H 2.8853900817779268f

__device__ __forceinline__ float fexp2(float x) {
#if __has_builtin(__builtin_amdgcn_exp2f)
    return __builtin_amdgcn_exp2f(x);
#else
    return __expf(x * 0.6931471805599453f);
#endif
}

// ---------------------------------------------------------------------------
// K0: transpose/convert params into MFMA-fragment-friendly fp16 layouts.
// Ut rows pre-scaled by log2e (z gate) / 2*log2e (h gate).
// ---------------------------------------------------------------------------
__global__ void k0_prep(const float* __restrict__ Uzf, const float* __restrict__ Uhf,
                        const float* __restrict__ Uzb, const float* __restrict__ Uhb,
                        const float* __restrict__ Wzf, const float* __restrict__ Whf,
                        const float* __restrict__ Wzb, const float* __restrict__ Whb,
                        const float* __restrict__ W1,
                        f16* __restrict__ Ut, f16* __restrict__ Wt, f16* __restrict__ W1t)
{
    int tid = blockIdx.x * blockDim.x + threadIdx.x;
    int nthr = gridDim.x * blockDim.x;
    for (int i = tid; i < 4 * 256 * 256; i += nthr) {
        int u = i >> 16, cc = (i >> 8) & 255, k = i & 255;
        const float* U = (u == 0) ? Uzf : (u == 1) ? Uhf : (u == 2) ? Uzb : Uhb;
        float sg = (u & 1) ? SCALE_H : SCALE_Z;   // u odd = h gate
        Ut[i] = (f16)(U[k * 256 + cc] * sg);
    }
    for (int i = tid; i < 2 * 512 * 128; i += nthr) {
        int dir = i >> 16, cc2 = (i >> 7) & 511, k = i & 127;
        const float* W = dir ? ((cc2 & 256) ? Whb : Wzb) : ((cc2 & 256) ? Whf : Wzf);
        Wt[i] = (f16)W[k * 256 + (cc2 & 255)];
    }
    for (int i = tid; i < 512 * 512; i += nthr) {
        int n = i >> 9, k = i & 511;
        W1t[i] = (f16)W1[k * 512 + n];
    }
}

// ---------------------------------------------------------------------------
// K1: input projections, LDS-free. One block = one (dir, g, s). Writes xp2 in
// K2's exact per-thread read layout; epilogue folds the exp2 scale.
// ---------------------------------------------------------------------------
__launch_bounds__(256, 2)
__global__ void k1_xproj(const float* __restrict__ x, const f16* __restrict__ Wt,
                         const float* __restrict__ bzf, const float* __restrict__ bhf,
                         const float* __restrict__ bzb, const float* __restrict__ bhb,
                         f16* __restrict__ xp2)
{
    int bid = blockIdx.x;
    int s = bid & 1023, g = (bid >> 10) & 3, dir = bid >> 12;
    int s_src = dir ? (1023 - s) : s;
    int tid = threadIdx.x, w = tid >> 6, lane = tid & 63, q = lane >> 4, l16 = lane & 15;

    f16x8 bf[4];
    const float* xr = x + ((size_t)(g * 16 + l16) * 1024 + s_src) * 128;
#pragma unroll
    for (int kt = 0; kt < 4; ++kt) {
        int k0 = kt * 32 + q * 8;
        f32x4 a = *(const f32x4*)(xr + k0);
        f32x4 c = *(const f32x4*)(xr + k0 + 4);
        f16x8 v;
#pragma unroll
        for (int j = 0; j < 4; ++j) { v[j] = (f16)a[j]; v[4 + j] = (f16)c[j]; }
        bf[kt] = v;
    }
    const f16* wt = Wt + (size_t)dir * 512 * 128;
    f16x8 af[8][4];
#pragma unroll
    for (int mt = 0; mt < 8; ++mt) {
        int cc2 = w * 128 + mt * 16 + l16;
#pragma unroll
        for (int kt = 0; kt < 4; ++kt)
            af[mt][kt] = *(const f16x8*)(wt + cc2 * 128 + kt * 32 + q * 8);
    }
    f32x4 acc[8];
#pragma unroll
    for (int mt = 0; mt < 8; ++mt) acc[mt] = (f32x4){0.f, 0.f, 0.f, 0.f};
#pragma unroll
    for (int kt = 0; kt < 4; ++kt)
#pragma unroll
        for (int mt = 0; mt < 8; ++mt)
            acc[mt] = MFMA16(af[mt][kt], bf[kt], acc[mt]);

    f16* dst = xp2 + (size_t)((dir * 4 + g) * 1024 + s) * 8192;
#pragma unroll
    for (int mt = 0; mt < 8; ++mt) {
        int ccg = w * 128 + mt * 16 + q * 4;
        int gate = ccg >> 8, c = ccg & 255;
        const float* bias = gate ? (dir ? bhb : bhf) : (dir ? bzb : bzf);
        float sg = gate ? SCALE_H : SCALE_Z;
        f32x4 bi = *(const f32x4*)(bias + c);
        f16x4 o;
#pragma unroll
        for (int r = 0; r < 4; ++r) o[r] = (f16)((acc[mt][r] + bi[r]) * sg);
        int flat = ((gate * 2 + ((c >> 4) & 1)) * 8 + (c >> 5)) * 256 + (q * 16 + l16) * 4;
        *(f16x4*)(dst + flat) = o;
    }
}

// ---------------------------------------------------------------------------
// K2: sequential recurrence, single barrier per step, phase-split for
// within-wave MFMA/VALU overlap, with the instruction interleave now ENFORCED
// by sched_group_barrier (R4 showed source order alone doesn't survive the
// scheduler). Template per step:
//   DS_READ x8 -> [MFMA2+VALU3]x8 (phase1 p0-chains, cvts/addr/prefetch in
//   the issue gaps) -> [MFMA2+VALU11]x4 (phase2 p1-chain pairs each carrying
//   one gate-p0 element) -> hh0 writes -> MFMA x8 -> VALU x44 (gate-p1) ->
//   writes. Order-only directive: semantics (and the proven race-freedom of
//   the R2 skeleton) unchanged.
// ---------------------------------------------------------------------------
#define GELEM(AZ, AH, HOLDV, HN, HH, R)                                       \
    {                                                                         \
        float E1 = fexp2(-(AZ)[R]);                                           \
        float E2 = fexp2(-(AH)[R]);                                           \
        float h0 = (HOLDV)[R];                                                \
        float num = __builtin_fmaf(h0, E2, h0) + __builtin_fmaf(-E1, E2, E1); \
        float den = (1.f + E1) * (1.f + E2);                                  \
        float hv = num * __builtin_amdgcn_rcpf(den);                          \
        (HN)[R] = hv; (HH)[R] = (f16)hv;                                      \
    }

#define GRU_STEP(P, SS, CX)                                                   \
    {                                                                         \
        const int cur = (P), nxt = (P) ^ 1;                                   \
        f16x8 bf[8];                                                          \
        _Pragma("unroll")                                                     \
        for (int j = 0; j < 8; ++j)                                           \
            bf[j] = *(const f16x8*)&h16[cur][l16][j * 32 + q * 8];            \
        f32x4 a0, a1, a2, a3;                                                 \
        _Pragma("unroll")                                                     \
        for (int r = 0; r < 4; ++r) {                                         \
            a0[r] = (float)CX[0][r]; a1[r] = (float)CX[1][r];                 \
            a2[r] = (float)CX[2][r]; a3[r] = (float)CX[3][r];                 \
        }                                                                     \
        int sp = (SS) + 2; if (sp > 1023) sp = 1023;                          \
        const f16* px = xb + (size_t)sp * 8192;                               \
        _Pragma("unroll")                                                     \
        for (int t = 0; t < 4; ++t) CX[t] = *(const f16x4*)(px + offs[t]);    \
        /* phase 1: p0 chains (t0 = z-p0, t2 = h-p0), 16 MFMA */              \
        _Pragma("unroll")                                                     \
        for (int j = 0; j < 8; ++j) {                                         \
            a0 = MFMA16(uf[0][j], bf[j], a0);                                 \
            a2 = MFMA16(uf[2][j], bf[j], a2);                                 \
        }                                                                     \
        /* phase 2: p1 chains (16 MFMA) interleaved with gate-p0 VALU */      \
        f32x4 hn0; f16x4 hh0;                                                 \
        a1 = MFMA16(uf[1][0], bf[0], a1); a3 = MFMA16(uf[3][0], bf[0], a3);   \
        GELEM(a0, a2, hold[0], hn0, hh0, 0)                                   \
        a1 = MFMA16(uf[1][1], bf[1], a1); a3 = MFMA16(uf[3][1], bf[1], a3);   \
        GELEM(a0, a2, hold[0], hn0, hh0, 1)                                   \
        a1 = MFMA16(uf[1][2], bf[2], a1); a3 = MFMA16(uf[3][2], bf[2], a3);   \
        GELEM(a0, a2, hold[0], hn0, hh0, 2)                                   \
        a1 = MFMA16(uf[1][3], bf[3], a1); a3 = MFMA16(uf[3][3], bf[3], a3);   \
        GELEM(a0, a2, hold[0], hn0, hh0, 3)                                   \
        hold[0] = hn0;                                                        \
        *(f16x4*)&h16[nxt][l16][ccg0] = hh0;                                  \
        *(f16x4*)(op) = hh0;                                                  \
        a1 = MFMA16(uf[1][4], bf[4], a1); a3 = MFMA16(uf[3][4], bf[4], a3);   \
        a1 = MFMA16(uf[1][5], bf[5], a1); a3 = MFMA16(uf[3][5], bf[5], a3);   \
        a1 = MFMA16(uf[1][6], bf[6], a1); a3 = MFMA16(uf[3][6], bf[6], a3);   \
        a1 = MFMA16(uf[1][7], bf[7], a1); a3 = MFMA16(uf[3][7], bf[7], a3);   \
        /* phase 3: gate p1 */                                                \
        f32x4 hn1; f16x4 hh1;                                                 \
        GELEM(a1, a3, hold[1], hn1, hh1, 0)                                   \
        GELEM(a1, a3, hold[1], hn1, hh1, 1)                                   \
        GELEM(a1, a3, hold[1], hn1, hh1, 2)                                   \
        GELEM(a1, a3, hold[1], hn1, hh1, 3)                                   \
        hold[1] = hn1;                                                        \
        *(f16x4*)&h16[nxt][l16][ccg0 + 16] = hh1;                             \
        *(f16x4*)(op + 16) = hh1;                                             \
        op += sstep;                                                          \
        /* ---- scheduling template (order-only) ---- */                      \
        SGB(SG_DS_RD, 8);                                                     \
        SGB(SG_VALU, 8);                 /* a0/a2 init cvts */                \
        SGB(SG_VMEM_RD, 4);              /* prefetch issue early */           \
        _Pragma("unroll")                                                     \
        for (int it = 0; it < 8; ++it) { SGB(SG_MFMA, 2); SGB(SG_VALU, 3); }  \
        _Pragma("unroll")                                                     \
        for (int it = 0; it < 4; ++it) { SGB(SG_MFMA, 2); SGB(SG_VALU, 11); } \
        SGB(SG_DS_WR, 1); SGB(SG_VMEM_WR, 1);                                 \
        SGB(SG_MFMA, 8);                                                      \
        SGB(SG_VALU, 44);                                                     \
        SGB(SG_DS_WR, 1); SGB(SG_VMEM_WR, 1);                                 \
        asm volatile("s_waitcnt lgkmcnt(0)" ::: "memory");                    \
        __builtin_amdgcn_s_barrier();                                         \
        asm volatile("" ::: "memory");                                        \
    }

__launch_bounds__(512, 2)
__global__ void k2_gru(const f16* __restrict__ Ut, const f16* __restrict__ xp2,
                       f16* __restrict__ out16)
{
    int bid = blockIdx.x;
    int dir = bid >> 2, g = bid & 3;
    int tid = threadIdx.x, w = tid >> 6, lane = tid & 63, q = lane >> 4, l16 = lane & 15;

    __shared__ f16 h16[2][16][264];   // double-buffered fp16 h

    for (int i = tid; i < 2 * 16 * 264; i += 512) (&h16[0][0][0])[i] = (f16)0.f;

    // resident U fragments. volatile: forbids rematerialization inside the
    // loop -> values stay resident (unified VGPR/AGPR file).
    f16x8 uf[4][8];
#pragma unroll
    for (int t = 0; t < 4; ++t) {
        int gate = t >> 1;
        int cc = w * 32 + (t & 1) * 16 + l16;
        const f16* up = Ut + ((size_t)(dir * 2 + gate) * 256 + cc) * 256;
#pragma unroll
        for (int j = 0; j < 8; ++j)
            uf[t][j] = *(const volatile f16x8*)(up + j * 32 + q * 8);
    }

    const f16* xb = xp2 + (size_t)(dir * 4 + g) * 1024 * 8192;
    int offs[4];
#pragma unroll
    for (int t = 0; t < 4; ++t) {
        int gate = t >> 1, p = t & 1;
        offs[t] = ((gate * 2 + p) * 8 + w) * 256 + lane * 4;
    }
    // depth-2 prefetch: cxA = even steps, cxB = odd steps
    f16x4 cxA[4], cxB[4];
#pragma unroll
    for (int t = 0; t < 4; ++t) cxA[t] = *(const f16x4*)(xb + offs[t]);
#pragma unroll
    for (int t = 0; t < 4; ++t) cxB[t] = *(const f16x4*)(xb + 8192 + offs[t]);

    f32x4 hold[2];
    hold[0] = (f32x4){0.f, 0.f, 0.f, 0.f};
    hold[1] = (f32x4){0.f, 0.f, 0.f, 0.f};

    // direct per-thread output pointer: row b = g*16+l16, col = dir*256+w*32+q*4
    f16* op = out16 + ((size_t)(g * 16 + l16) * 1024 + (dir ? 1023 : 0)) * 512
            + dir * 256 + w * 32 + q * 4;
    ptrdiff_t sstep = dir ? -512 : 512;
    int ccg0 = w * 32 + q * 4;

    __syncthreads();   // h16 zero-init visible (once; full drain fine here)

    for (int s = 0; s < 1024; s += 2) {
        GRU_STEP(0, s, cxA)
        GRU_STEP(1, s + 1, cxB)
    }
}

// ---------------------------------------------------------------------------
// K3a: scores = tanh(out @ W1 + b1) @ w2 + b2.
// ---------------------------------------------------------------------------
__launch_bounds__(256, 2)
__global__ void k3_scores(const f16* __restrict__ out16, const f16* __restrict__ W1t,
                          const float* __restrict__ b1, const float* __restrict__ w2,
                          const float* __restrict__ b2, float* __restrict__ scores)
{
    int bid = blockIdx.x;
    int b = bid >> 4, sc = bid & 15, s0 = sc * 64;
    int tid = threadIdx.x, w = tid >> 6, lane = tid & 63, q = lane >> 4, l16 = lane & 15;
    f32x4 acc[4][8];
#pragma unroll
    for (int mt = 0; mt < 4; ++mt)
#pragma unroll
        for (int nt = 0; nt < 8; ++nt) acc[mt][nt] = (f32x4){0.f, 0.f, 0.f, 0.f};

    for (int kt = 0; kt < 16; ++kt) {
        f16x8 af[4];
#pragma unroll
        for (int mt = 0; mt < 4; ++mt) {
            size_t row = (size_t)b * 1024 + s0 + mt * 16 + l16;
            af[mt] = *(const f16x8*)(out16 + row * 512 + kt * 32 + q * 8);
        }
        f16x8 bfg[8];
#pragma unroll
        for (int nt = 0; nt < 8; ++nt) {
            int ncol = w * 128 + nt * 16 + l16;
            bfg[nt] = *(const f16x8*)(W1t + (size_t)ncol * 512 + kt * 32 + q * 8);
        }
#pragma unroll
        for (int mt = 0; mt < 4; ++mt)
#pragma unroll
            for (int nt = 0; nt < 8; ++nt)
                acc[mt][nt] = MFMA16(af[mt], bfg[nt], acc[mt][nt]);
    }
    float b1v[8], w2v[8];
#pragma unroll
    for (int nt = 0; nt < 8; ++nt) {
        int ncol = w * 128 + nt * 16 + l16;
        b1v[nt] = b1[ncol];
        w2v[nt] = w2[ncol];
    }
    __shared__ float spart[4][64];
    float rs[4][4];
#pragma unroll
    for (int mt = 0; mt < 4; ++mt)
#pragma unroll
        for (int r = 0; r < 4; ++r) {
            float ssum = 0.f;
#pragma unroll
            for (int nt = 0; nt < 8; ++nt) {
                float xv = acc[mt][nt][r] + b1v[nt];
                float t = 1.f - 2.f / (1.f + __expf(2.f * xv));
                ssum += t * w2v[nt];
            }
            rs[mt][r] = ssum;
        }
#pragma unroll
    for (int off = 1; off < 16; off <<= 1)
#pragma unroll
        for (int mt = 0; mt < 4; ++mt)
#pragma unroll
            for (int r = 0; r < 4; ++r)
                rs[mt][r] += __shfl_xor(rs[mt][r], off, 64);
    if (l16 == 0) {
#pragma unroll
        for (int mt = 0; mt < 4; ++mt)
#pragma unroll
            for (int r = 0; r < 4; ++r)
                spart[w][mt * 16 + q * 4 + r] = rs[mt][r];
    }
    __syncthreads();
    if (tid < 64) {
        float v = spart[0][tid] + spart[1][tid] + spart[2][tid] + spart[3][tid] + b2[0];
        scores[b * 1024 + s0 + tid] = v;
    }
}

// K3b1: softmax over time per batch.
__global__ void k3_softmax(const float* __restrict__ scores, float* __restrict__ attn)
{
    int b = blockIdx.x, tid = threadIdx.x;
    __shared__ float red[4];
    f32x4 v = *(const f32x4*)(scores + b * 1024 + tid * 4);
    float m = fmaxf(fmaxf(v[0], v[1]), fmaxf(v[2], v[3]));
#pragma unroll
    for (int off = 1; off < 64; off <<= 1) m = fmaxf(m, __shfl_xor(m, off, 64));
    if ((tid & 63) == 0) red[tid >> 6] = m;
    __syncthreads();
    m = fmaxf(fmaxf(red[0], red[1]), fmaxf(red[2], red[3]));
    __syncthreads();
    float e0 = __expf(v[0] - m), e1 = __expf(v[1] - m), e2 = __expf(v[2] - m), e3 = __expf(v[3] - m);
    float ssum = e0 + e1 + e2 + e3;
#pragma unroll
    for (int off = 1; off < 64; off <<= 1) ssum += __shfl_xor(ssum, off, 64);
    if ((tid & 63) == 0) red[tid >> 6] = ssum;
    __syncthreads();
    float inv = 1.f / (red[0] + red[1] + red[2] + red[3]);
    f32x4 o = {e0 * inv, e1 * inv, e2 * inv, e3 * inv};
    *(f32x4*)(attn + b * 1024 + tid * 4) = o;
}

// K3b2: partial weighted sums over s-chunks of 128.
__global__ void k3_wsum(const f16* __restrict__ out16, const float* __restrict__ attn,
                        float* __restrict__ part)
{
    int bid = blockIdx.x;
    int b = bid >> 3, ch = bid & 7;
    int tid = threadIdx.x;
    const f16* op = out16 + ((size_t)b * 1024 + ch * 128) * 512 + tid * 2;
    const float* ap = attn + b * 1024 + ch * 128;
    float a0 = 0.f, a1 = 0.f;
#pragma unroll 4
    for (int i = 0; i < 128; ++i) {
        float aw = ap[i];
        f16x2 xv = *(const f16x2*)(op + (size_t)i * 512);
        a0 += aw * (float)xv[0];
        a1 += aw * (float)xv[1];
    }
    part[(size_t)(b * 8 + ch) * 512 + tid * 2] = a0;
    part[(size_t)(b * 8 + ch) * 512 + tid * 2 + 1] = a1;
}

// K3b3: reduce 8 partials -> context (fp32 output).
__global__ void k3_final(const float* __restrict__ part, float* __restrict__ outp)
{
    int b = blockIdx.x, tid = threadIdx.x;
#pragma unroll
    for (int j = 0; j < 2; ++j) {
        int cc = tid * 2 + j;
        float ssum = 0.f;
#pragma unroll
        for (int ch = 0; ch < 8; ++ch) ssum += part[(size_t)(b * 8 + ch) * 512 + cc];
        outp[b * 512 + cc] = ssum;
    }
}

extern "C" void kernel_launch(void* const* d_in, const int* in_sizes, int n_in,
                              void* d_out, int out_size, void* d_ws, size_t ws_size,
                              hipStream_t stream)
{
    const float* x   = (const float*)d_in[0];
    const float* Wzf = (const float*)d_in[1];
    const float* Uzf = (const float*)d_in[2];
    const float* bzf = (const float*)d_in[3];
    const float* Whf = (const float*)d_in[4];
    const float* Uhf = (const float*)d_in[5];
    const float* bhf = (const float*)d_in[6];
    const float* Wzb = (const float*)d_in[7];
    const float* Uzb = (const float*)d_in[8];
    const float* bzb = (const float*)d_in[9];
    const float* Whb = (const float*)d_in[10];
    const float* Uhb = (const float*)d_in[11];
    const float* bhb = (const float*)d_in[12];
    const float* W1  = (const float*)d_in[13];
    const float* b1  = (const float*)d_in[14];
    const float* w2  = (const float*)d_in[15];
    const float* b2  = (const float*)d_in[16];
    float* outp = (float*)d_out;

    char* ws = (char*)d_ws;
    f16* Ut    = (f16*)(ws + UT_OFF);
    f16* Wt    = (f16*)(ws + WT_OFF);
    f16* W1t   = (f16*)(ws + W1T_OFF);
    f16* xp2   = (f16*)(ws + XP_OFF);
    f16* o16   = (f16*)(ws + OUT_OFF);
    float* sc  = (float*)(ws + SC_OFF);
    float* at  = (float*)(ws + AT_OFF);
    float* pt  = (float*)(ws + PART_OFF);

    hipLaunchKernelGGL(k0_prep, dim3(256), dim3(256), 0, stream,
                       Uzf, Uhf, Uzb, Uhb, Wzf, Whf, Wzb, Whb, W1, Ut, Wt, W1t);
    hipLaunchKernelGGL(k1_xproj, dim3(8192), dim3(256), 0, stream,
                       x, Wt, bzf, bhf, bzb, bhb, xp2);
    hipLaunchKernelGGL(k2_gru, dim3(8), dim3(512), 0, stream, Ut, xp2, o16);
    hipLaunchKernelGGL(k3_scores, dim3(1024), dim3(256), 0, stream, o16, W1t, b1, w2, b2, sc);
    hipLaunchKernelGGL(k3_softmax, dim3(64), dim3(256), 0, stream, sc, at);
    hipLaunchKernelGGL(k3_wsum, dim3(512), dim3(256), 0, stream, o16, at, pt);
    hipLaunchKernelGGL(k3_final, dim3(64), dim3(256), 0, stream, pt, outp);
}

// Round 6
// 1398.783 us; speedup vs baseline: 1.0415x; 1.0415x over previous
//
#include <hip/hip_runtime.h>
#include <cstdint>
#include <cstddef>

typedef _Float16 f16;
typedef _Float16 f16x8 __attribute__((ext_vector_type(8)));
typedef _Float16 f16x4 __attribute__((ext_vector_type(4)));
typedef _Float16 f16x2 __attribute__((ext_vector_type(2)));
typedef float f32x4 __attribute__((ext_vector_type(4)));

#define MFMA16(a, b, c) __builtin_amdgcn_mfma_f32_16x16x32_f16((a), (b), (c), 0, 0, 0)

// Problem sizes: B=64, S=1024, D=128, H=256, 2H=512

// Workspace layout (bytes). Total ~194.8 MiB.
static constexpr size_t UT_OFF  = 0;                         // Ut  [2dir][2gate][256cc][256k] f16 = 524288
static constexpr size_t WT_OFF  = 524288;                    // Wt  [2dir][512cc2][128k] f16   = 262144
static constexpr size_t W1T_OFF = 786432;                    // W1t [512n][512k] f16           = 524288
static constexpr size_t XP_OFF  = 1310720;                   // xp2 [2dir*4g][1024s][8192] f16 = 134217728
static constexpr size_t OUT_OFF = XP_OFF + 134217728;        // out16 [64b][1024s][512] f16    = 67108864
static constexpr size_t SC_OFF  = OUT_OFF + 67108864;        // scores [64][1024] f32          = 262144
static constexpr size_t AT_OFF  = SC_OFF + 262144;           // attn   [64][1024] f32          = 262144
static constexpr size_t PART_OFF= AT_OFF + 262144;           // partials [64][8][512] f32      = 1048576

// log2(e) folded into z-path, 2*log2(e) into h-path so the recurrence uses raw
// v_exp_f32 (2^x) with no per-element scale mul.
#define SCALE_Z 1.4426950408889634f
#define SCALE_H 2.8853900817779268f

__device__ __forceinline__ float fexp2(float x) {
#if __has_builtin(__builtin_amdgcn_exp2f)
    return __builtin_amdgcn_exp2f(x);
#else
    return __expf(x * 0.6931471805599453f);
#endif
}

// ---------------------------------------------------------------------------
// K0: transpose/convert params into MFMA-fragment-friendly fp16 layouts.
// Ut rows pre-scaled by log2e (z gate) / 2*log2e (h gate).
// ---------------------------------------------------------------------------
__global__ void k0_prep(const float* __restrict__ Uzf, const float* __restrict__ Uhf,
                        const float* __restrict__ Uzb, const float* __restrict__ Uhb,
                        const float* __restrict__ Wzf, const float* __restrict__ Whf,
                        const float* __restrict__ Wzb, const float* __restrict__ Whb,
                        const float* __restrict__ W1,
                        f16* __restrict__ Ut, f16* __restrict__ Wt, f16* __restrict__ W1t)
{
    int tid = blockIdx.x * blockDim.x + threadIdx.x;
    int nthr = gridDim.x * blockDim.x;
    for (int i = tid; i < 4 * 256 * 256; i += nthr) {
        int u = i >> 16, cc = (i >> 8) & 255, k = i & 255;
        const float* U = (u == 0) ? Uzf : (u == 1) ? Uhf : (u == 2) ? Uzb : Uhb;
        float sg = (u & 1) ? SCALE_H : SCALE_Z;   // u odd = h gate
        Ut[i] = (f16)(U[k * 256 + cc] * sg);
    }
    for (int i = tid; i < 2 * 512 * 128; i += nthr) {
        int dir = i >> 16, cc2 = (i >> 7) & 511, k = i & 127;
        const float* W = dir ? ((cc2 & 256) ? Whb : Wzb) : ((cc2 & 256) ? Whf : Wzf);
        Wt[i] = (f16)W[k * 256 + (cc2 & 255)];
    }
    for (int i = tid; i < 512 * 512; i += nthr) {
        int n = i >> 9, k = i & 511;
        W1t[i] = (f16)W1[k * 512 + n];
    }
}

// ---------------------------------------------------------------------------
// K1: input projections, LDS-free. One block = one (dir, g, s). Writes xp2 in
// K2's exact per-thread read layout; epilogue folds the exp2 scale.
// ---------------------------------------------------------------------------
__launch_bounds__(256, 2)
__global__ void k1_xproj(const float* __restrict__ x, const f16* __restrict__ Wt,
                         const float* __restrict__ bzf, const float* __restrict__ bhf,
                         const float* __restrict__ bzb, const float* __restrict__ bhb,
                         f16* __restrict__ xp2)
{
    int bid = blockIdx.x;
    int s = bid & 1023, g = (bid >> 10) & 3, dir = bid >> 12;
    int s_src = dir ? (1023 - s) : s;
    int tid = threadIdx.x, w = tid >> 6, lane = tid & 63, q = lane >> 4, l16 = lane & 15;

    f16x8 bf[4];
    const float* xr = x + ((size_t)(g * 16 + l16) * 1024 + s_src) * 128;
#pragma unroll
    for (int kt = 0; kt < 4; ++kt) {
        int k0 = kt * 32 + q * 8;
        f32x4 a = *(const f32x4*)(xr + k0);
        f32x4 c = *(const f32x4*)(xr + k0 + 4);
        f16x8 v;
#pragma unroll
        for (int j = 0; j < 4; ++j) { v[j] = (f16)a[j]; v[4 + j] = (f16)c[j]; }
        bf[kt] = v;
    }
    const f16* wt = Wt + (size_t)dir * 512 * 128;
    f16x8 af[8][4];
#pragma unroll
    for (int mt = 0; mt < 8; ++mt) {
        int cc2 = w * 128 + mt * 16 + l16;
#pragma unroll
        for (int kt = 0; kt < 4; ++kt)
            af[mt][kt] = *(const f16x8*)(wt + cc2 * 128 + kt * 32 + q * 8);
    }
    f32x4 acc[8];
#pragma unroll
    for (int mt = 0; mt < 8; ++mt) acc[mt] = (f32x4){0.f, 0.f, 0.f, 0.f};
#pragma unroll
    for (int kt = 0; kt < 4; ++kt)
#pragma unroll
        for (int mt = 0; mt < 8; ++mt)
            acc[mt] = MFMA16(af[mt][kt], bf[kt], acc[mt]);

    f16* dst = xp2 + (size_t)((dir * 4 + g) * 1024 + s) * 8192;
#pragma unroll
    for (int mt = 0; mt < 8; ++mt) {
        int ccg = w * 128 + mt * 16 + q * 4;
        int gate = ccg >> 8, c = ccg & 255;
        const float* bias = gate ? (dir ? bhb : bhf) : (dir ? bzb : bzf);
        float sg = gate ? SCALE_H : SCALE_Z;
        f32x4 bi = *(const f32x4*)(bias + c);
        f16x4 o;
#pragma unroll
        for (int r = 0; r < 4; ++r) o[r] = (f16)((acc[mt][r] + bi[r]) * sg);
        int flat = ((gate * 2 + ((c >> 4) & 1)) * 8 + (c >> 5)) * 256 + (q * 16 + l16) * 4;
        *(f16x4*)(dst + flat) = o;
    }
}

// ---------------------------------------------------------------------------
// K2: sequential recurrence — the proven single-barrier lockstep skeleton
// (R2, 941us), with one deterministic VALU reduction: paired reciprocal.
// Gate math per element pair (p=0 and p=1 of the same r):
//   E1 = 2^(-az'), E2 = 2^(-ah'), num = h(1+E2)+E1(1-E2),
//   den = (1+E1)(1+E2); both hv share ONE rcp via inv = rcp(den0*den1),
//   hv0 = num0*inv*den1, hv1 = num1*inv*den0.
// Cuts 8 rcp/thread/step -> 4 (transcendentals dominate the VALU pipe).
// Overflow-safe: den <= ~2^20 for N(0,1)-scale activations -> product well
// inside f32 range; rcp's ~1ulp error is far below f16 h-storage rounding.
// Raw s_barrier with lgkmcnt(0) only; depth-2 xp2 prefetch (cxA/cxB parity).
// ---------------------------------------------------------------------------
#define GELEM2(R)                                                             \
    {                                                                         \
        float E1a = fexp2(-acc[0][R]);                                        \
        float E2a = fexp2(-acc[2][R]);                                        \
        float E1b = fexp2(-acc[1][R]);                                        \
        float E2b = fexp2(-acc[3][R]);                                        \
        float h0a = hold[0][R], h0b = hold[1][R];                             \
        float numa = __builtin_fmaf(h0a, E2a, h0a)                            \
                   + __builtin_fmaf(-E1a, E2a, E1a);                          \
        float dena = (1.f + E1a) * (1.f + E2a);                               \
        float numb = __builtin_fmaf(h0b, E2b, h0b)                            \
                   + __builtin_fmaf(-E1b, E2b, E1b);                          \
        float denb = (1.f + E1b) * (1.f + E2b);                               \
        float inv = __builtin_amdgcn_rcpf(dena * denb);                       \
        float hva = numa * inv * denb;                                        \
        float hvb = numb * inv * dena;                                        \
        hn0[R] = hva; hh0[R] = (f16)hva;                                      \
        hn1[R] = hvb; hh1[R] = (f16)hvb;                                      \
    }

#define GRU_STEP(P, SS, CX)                                                   \
    {                                                                         \
        const int cur = (P), nxt = (P) ^ 1;                                   \
        f16x8 bf[8];                                                          \
        _Pragma("unroll")                                                     \
        for (int j = 0; j < 8; ++j)                                           \
            bf[j] = *(const f16x8*)&h16[cur][l16][j * 32 + q * 8];            \
        f32x4 acc[4];                                                         \
        _Pragma("unroll")                                                     \
        for (int t = 0; t < 4; ++t)                                           \
            _Pragma("unroll")                                                 \
            for (int r = 0; r < 4; ++r) acc[t][r] = (float)CX[t][r];          \
        int sp = (SS) + 2; if (sp > 1023) sp = 1023;                          \
        const f16* px = xb + (size_t)sp * 8192;                               \
        _Pragma("unroll")                                                     \
        for (int t = 0; t < 4; ++t) CX[t] = *(const f16x4*)(px + offs[t]);    \
        _Pragma("unroll")                                                     \
        for (int j = 0; j < 8; ++j)                                           \
            _Pragma("unroll")                                                 \
            for (int t = 0; t < 4; ++t)                                       \
                acc[t] = MFMA16(uf[t][j], bf[j], acc[t]);                     \
        f32x4 hn0, hn1; f16x4 hh0, hh1;                                       \
        GELEM2(0)                                                             \
        GELEM2(1)                                                             \
        GELEM2(2)                                                             \
        GELEM2(3)                                                             \
        hold[0] = hn0; hold[1] = hn1;                                         \
        *(f16x4*)&h16[nxt][l16][ccg0] = hh0;                                  \
        *(f16x4*)(op) = hh0;                                                  \
        *(f16x4*)&h16[nxt][l16][ccg0 + 16] = hh1;                             \
        *(f16x4*)(op + 16) = hh1;                                             \
        op += sstep;                                                          \
        asm volatile("s_waitcnt lgkmcnt(0)" ::: "memory");                    \
        __builtin_amdgcn_s_barrier();                                         \
        asm volatile("" ::: "memory");                                        \
    }

__launch_bounds__(512, 2)
__global__ void k2_gru(const f16* __restrict__ Ut, const f16* __restrict__ xp2,
                       f16* __restrict__ out16)
{
    int bid = blockIdx.x;
    int dir = bid >> 2, g = bid & 3;
    int tid = threadIdx.x, w = tid >> 6, lane = tid & 63, q = lane >> 4, l16 = lane & 15;

    __shared__ f16 h16[2][16][264];   // double-buffered fp16 h

    for (int i = tid; i < 2 * 16 * 264; i += 512) (&h16[0][0][0])[i] = (f16)0.f;

    // resident U fragments. volatile: forbids rematerialization inside the
    // loop -> values stay resident (unified VGPR/AGPR file).
    f16x8 uf[4][8];
#pragma unroll
    for (int t = 0; t < 4; ++t) {
        int gate = t >> 1;
        int cc = w * 32 + (t & 1) * 16 + l16;
        const f16* up = Ut + ((size_t)(dir * 2 + gate) * 256 + cc) * 256;
#pragma unroll
        for (int j = 0; j < 8; ++j)
            uf[t][j] = *(const volatile f16x8*)(up + j * 32 + q * 8);
    }

    const f16* xb = xp2 + (size_t)(dir * 4 + g) * 1024 * 8192;
    int offs[4];
#pragma unroll
    for (int t = 0; t < 4; ++t) {
        int gate = t >> 1, p = t & 1;
        offs[t] = ((gate * 2 + p) * 8 + w) * 256 + lane * 4;
    }
    // depth-2 prefetch: cxA = even steps, cxB = odd steps
    f16x4 cxA[4], cxB[4];
#pragma unroll
    for (int t = 0; t < 4; ++t) cxA[t] = *(const f16x4*)(xb + offs[t]);
#pragma unroll
    for (int t = 0; t < 4; ++t) cxB[t] = *(const f16x4*)(xb + 8192 + offs[t]);

    f32x4 hold[2];
    hold[0] = (f32x4){0.f, 0.f, 0.f, 0.f};
    hold[1] = (f32x4){0.f, 0.f, 0.f, 0.f};

    // direct per-thread output pointer: row b = g*16+l16, col = dir*256+w*32+q*4
    f16* op = out16 + ((size_t)(g * 16 + l16) * 1024 + (dir ? 1023 : 0)) * 512
            + dir * 256 + w * 32 + q * 4;
    ptrdiff_t sstep = dir ? -512 : 512;
    int ccg0 = w * 32 + q * 4;

    __syncthreads();   // h16 zero-init visible (once; full drain fine here)

    for (int s = 0; s < 1024; s += 2) {
        GRU_STEP(0, s, cxA)
        GRU_STEP(1, s + 1, cxB)
    }
}

// ---------------------------------------------------------------------------
// K3a: scores = tanh(out @ W1 + b1) @ w2 + b2.
// ---------------------------------------------------------------------------
__launch_bounds__(256, 2)
__global__ void k3_scores(const f16* __restrict__ out16, const f16* __restrict__ W1t,
                          const float* __restrict__ b1, const float* __restrict__ w2,
                          const float* __restrict__ b2, float* __restrict__ scores)
{
    int bid = blockIdx.x;
    int b = bid >> 4, sc = bid & 15, s0 = sc * 64;
    int tid = threadIdx.x, w = tid >> 6, lane = tid & 63, q = lane >> 4, l16 = lane & 15;
    f32x4 acc[4][8];
#pragma unroll
    for (int mt = 0; mt < 4; ++mt)
#pragma unroll
        for (int nt = 0; nt < 8; ++nt) acc[mt][nt] = (f32x4){0.f, 0.f, 0.f, 0.f};

    for (int kt = 0; kt < 16; ++kt) {
        f16x8 af[4];
#pragma unroll
        for (int mt = 0; mt < 4; ++mt) {
            size_t row = (size_t)b * 1024 + s0 + mt * 16 + l16;
            af[mt] = *(const f16x8*)(out16 + row * 512 + kt * 32 + q * 8);
        }
        f16x8 bfg[8];
#pragma unroll
        for (int nt = 0; nt < 8; ++nt) {
            int ncol = w * 128 + nt * 16 + l16;
            bfg[nt] = *(const f16x8*)(W1t + (size_t)ncol * 512 + kt * 32 + q * 8);
        }
#pragma unroll
        for (int mt = 0; mt < 4; ++mt)
#pragma unroll
            for (int nt = 0; nt < 8; ++nt)
                acc[mt][nt] = MFMA16(af[mt], bfg[nt], acc[mt][nt]);
    }
    float b1v[8], w2v[8];
#pragma unroll
    for (int nt = 0; nt < 8; ++nt) {
        int ncol = w * 128 + nt * 16 + l16;
        b1v[nt] = b1[ncol];
        w2v[nt] = w2[ncol];
    }
    __shared__ float spart[4][64];
    float rs[4][4];
#pragma unroll
    for (int mt = 0; mt < 4; ++mt)
#pragma unroll
        for (int r = 0; r < 4; ++r) {
            float ssum = 0.f;
#pragma unroll
            for (int nt = 0; nt < 8; ++nt) {
                float xv = acc[mt][nt][r] + b1v[nt];
                float t = 1.f - 2.f / (1.f + __expf(2.f * xv));
                ssum += t * w2v[nt];
            }
            rs[mt][r] = ssum;
        }
#pragma unroll
    for (int off = 1; off < 16; off <<= 1)
#pragma unroll
        for (int mt = 0; mt < 4; ++mt)
#pragma unroll
            for (int r = 0; r < 4; ++r)
                rs[mt][r] += __shfl_xor(rs[mt][r], off, 64);
    if (l16 == 0) {
#pragma unroll
        for (int mt = 0; mt < 4; ++mt)
#pragma unroll
            for (int r = 0; r < 4; ++r)
                spart[w][mt * 16 + q * 4 + r] = rs[mt][r];
    }
    __syncthreads();
    if (tid < 64) {
        float v = spart[0][tid] + spart[1][tid] + spart[2][tid] + spart[3][tid] + b2[0];
        scores[b * 1024 + s0 + tid] = v;
    }
}

// K3b1: softmax over time per batch.
__global__ void k3_softmax(const float* __restrict__ scores, float* __restrict__ attn)
{
    int b = blockIdx.x, tid = threadIdx.x;
    __shared__ float red[4];
    f32x4 v = *(const f32x4*)(scores + b * 1024 + tid * 4);
    float m = fmaxf(fmaxf(v[0], v[1]), fmaxf(v[2], v[3]));
#pragma unroll
    for (int off = 1; off < 64; off <<= 1) m = fmaxf(m, __shfl_xor(m, off, 64));
    if ((tid & 63) == 0) red[tid >> 6] = m;
    __syncthreads();
    m = fmaxf(fmaxf(red[0], red[1]), fmaxf(red[2], red[3]));
    __syncthreads();
    float e0 = __expf(v[0] - m), e1 = __expf(v[1] - m), e2 = __expf(v[2] - m), e3 = __expf(v[3] - m);
    float ssum = e0 + e1 + e2 + e3;
#pragma unroll
    for (int off = 1; off < 64; off <<= 1) ssum += __shfl_xor(ssum, off, 64);
    if ((tid & 63) == 0) red[tid >> 6] = ssum;
    __syncthreads();
    float inv = 1.f / (red[0] + red[1] + red[2] + red[3]);
    f32x4 o = {e0 * inv, e1 * inv, e2 * inv, e3 * inv};
    *(f32x4*)(attn + b * 1024 + tid * 4) = o;
}

// K3b2: partial weighted sums over s-chunks of 128.
__global__ void k3_wsum(const f16* __restrict__ out16, const float* __restrict__ attn,
                        float* __restrict__ part)
{
    int bid = blockIdx.x;
    int b = bid >> 3, ch = bid & 7;
    int tid = threadIdx.x;
    const f16* op = out16 + ((size_t)b * 1024 + ch * 128) * 512 + tid * 2;
    const float* ap = attn + b * 1024 + ch * 128;
    float a0 = 0.f, a1 = 0.f;
#pragma unroll 4
    for (int i = 0; i < 128; ++i) {
        float aw = ap[i];
        f16x2 xv = *(const f16x2*)(op + (size_t)i * 512);
        a0 += aw * (float)xv[0];
        a1 += aw * (float)xv[1];
    }
    part[(size_t)(b * 8 + ch) * 512 + tid * 2] = a0;
    part[(size_t)(b * 8 + ch) * 512 + tid * 2 + 1] = a1;
}

// K3b3: reduce 8 partials -> context (fp32 output).
__global__ void k3_final(const float* __restrict__ part, float* __restrict__ outp)
{
    int b = blockIdx.x, tid = threadIdx.x;
#pragma unroll
    for (int j = 0; j < 2; ++j) {
        int cc = tid * 2 + j;
        float ssum = 0.f;
#pragma unroll
        for (int ch = 0; ch < 8; ++ch) ssum += part[(size_t)(b * 8 + ch) * 512 + cc];
        outp[b * 512 + cc] = ssum;
    }
}

extern "C" void kernel_launch(void* const* d_in, const int* in_sizes, int n_in,
                              void* d_out, int out_size, void* d_ws, size_t ws_size,
                              hipStream_t stream)
{
    const float* x   = (const float*)d_in[0];
    const float* Wzf = (const float*)d_in[1];
    const float* Uzf = (const float*)d_in[2];
    const float* bzf = (const float*)d_in[3];
    const float* Whf = (const float*)d_in[4];
    const float* Uhf = (const float*)d_in[5];
    const float* bhf = (const float*)d_in[6];
    const float* Wzb = (const float*)d_in[7];
    const float* Uzb = (const float*)d_in[8];
    const float* bzb = (const float*)d_in[9];
    const float* Whb = (const float*)d_in[10];
    const float* Uhb = (const float*)d_in[11];
    const float* bhb = (const float*)d_in[12];
    const float* W1  = (const float*)d_in[13];
    const float* b1  = (const float*)d_in[14];
    const float* w2  = (const float*)d_in[15];
    const float* b2  = (const float*)d_in[16];
    float* outp = (float*)d_out;

    char* ws = (char*)d_ws;
    f16* Ut    = (f16*)(ws + UT_OFF);
    f16* Wt    = (f16*)(ws + WT_OFF);
    f16* W1t   = (f16*)(ws + W1T_OFF);
    f16* xp2   = (f16*)(ws + XP_OFF);
    f16* o16   = (f16*)(ws + OUT_OFF);
    float* sc  = (float*)(ws + SC_OFF);
    float* at  = (float*)(ws + AT_OFF);
    float* pt  = (float*)(ws + PART_OFF);

    hipLaunchKernelGGL(k0_prep, dim3(256), dim3(256), 0, stream,
                       Uzf, Uhf, Uzb, Uhb, Wzf, Whf, Wzb, Whb, W1, Ut, Wt, W1t);
    hipLaunchKernelGGL(k1_xproj, dim3(8192), dim3(256), 0, stream,
                       x, Wt, bzf, bhf, bzb, bhb, xp2);
    hipLaunchKernelGGL(k2_gru, dim3(8), dim3(512), 0, stream, Ut, xp2, o16);
    hipLaunchKernelGGL(k3_scores, dim3(1024), dim3(256), 0, stream, o16, W1t, b1, w2, b2, sc);
    hipLaunchKernelGGL(k3_softmax, dim3(64), dim3(256), 0, stream, sc, at);
    hipLaunchKernelGGL(k3_wsum, dim3(512), dim3(256), 0, stream, o16, at, pt);
    hipLaunchKernelGGL(k3_final, dim3(64), dim3(256), 0, stream, pt, outp);
}

// Round 8
// 1234.468 us; speedup vs baseline: 1.1801x; 1.1331x over previous
//
#include <hip/hip_runtime.h>
#include <cstdint>
#include <cstddef>

typedef _Float16 f16;
typedef _Float16 f16x8 __attribute__((ext_vector_type(8)));
typedef _Float16 f16x4 __attribute__((ext_vector_type(4)));
typedef _Float16 f16x2 __attribute__((ext_vector_type(2)));
typedef float f32x4 __attribute__((ext_vector_type(4)));
typedef int i32x4 __attribute__((ext_vector_type(4)));

#define MFMA16(a, b, c) __builtin_amdgcn_mfma_f32_16x16x32_f16((a), (b), (c), 0, 0, 0)
#define MFMAI8(a, b, c) __builtin_amdgcn_mfma_i32_16x16x64_i8((a), (b), (c), 0, 0, 0)

// Problem sizes: B=64, S=1024, D=128, H=256, 2H=512

// Workspace layout (bytes). Total ~194.8 MiB.
static constexpr size_t UT8_OFF = 0;                         // Ut8 [2dir*2gate][256cc][256k] i8 = 262144
static constexpr size_t USCL_OFF= 262144;                    // uscl [2dir*2gate][256cc] f32    = 4096
static constexpr size_t WT_OFF  = 524288;                    // Wt  [2dir][512cc2][128k] f16   = 262144
static constexpr size_t W1T_OFF = 786432;                    // W1t [512n][512k] f16           = 524288
static constexpr size_t XP_OFF  = 1310720;                   // xp2 [2dir*4g][1024s][8192] f16 = 134217728
static constexpr size_t OUT_OFF = XP_OFF + 134217728;        // out16 [64b][1024s][512] f16    = 67108864
static constexpr size_t SC_OFF  = OUT_OFF + 67108864;        // scores [64][1024] f32          = 262144
static constexpr size_t AT_OFF  = SC_OFF + 262144;           // attn   [64][1024] f32          = 262144
static constexpr size_t PART_OFF= AT_OFF + 262144;           // partials [64][8][512] f32      = 1048576

// log2(e) folded into z-path, 2*log2(e) into h-path so the recurrence uses raw
// v_exp_f32 (2^x) with no per-element scale mul. For the i8 U-path the same
// factor is folded into the per-row dequant scale (uscl).
#define SCALE_Z 1.4426950408889634f
#define SCALE_H 2.8853900817779268f
#define QMAGIC 12582912.0f   // 1.5*2^23: bits(QMAGIC+n) = 0x4B400000+n (RNE round)

__device__ __forceinline__ float fexp2(float x) {
#if __has_builtin(__builtin_amdgcn_exp2f)
    return __builtin_amdgcn_exp2f(x);
#else
    return __expf(x * 0.6931471805599453f);
#endif
}

// ---------------------------------------------------------------------------
// K0: param prep. U -> transposed i8 rows with per-(gate,cc) scale (one wave
// per row: lanes cover k, shfl-max reduce, magic-round quantize, coalesced
// 4B/lane stores). W / W1 -> transposed f16 (unchanged).
// ---------------------------------------------------------------------------
__global__ void k0_prep(const float* __restrict__ Uzf, const float* __restrict__ Uhf,
                        const float* __restrict__ Uzb, const float* __restrict__ Uhb,
                        const float* __restrict__ Wzf, const float* __restrict__ Whf,
                        const float* __restrict__ Wzb, const float* __restrict__ Whb,
                        const float* __restrict__ W1,
                        char* __restrict__ Ut8, float* __restrict__ uscl,
                        f16* __restrict__ Wt, f16* __restrict__ W1t)
{
    int tid = blockIdx.x * blockDim.x + threadIdx.x;
    int nthr = gridDim.x * blockDim.x;
    // i8 quant: row i = (u = dir*2+gate)*256 + cc; lane covers k = lane*4..+3
    {
        int wid = tid >> 6, lane = tid & 63, nw = nthr >> 6;
        for (int i = wid; i < 4 * 256; i += nw) {
            int u = i >> 8, cc = i & 255;
            const float* U = (u == 0) ? Uzf : (u == 1) ? Uhf : (u == 2) ? Uzb : Uhb;
            float v[4]; float mx = 0.f;
#pragma unroll
            for (int j = 0; j < 4; ++j) {
                v[j] = U[(lane * 4 + j) * 256 + cc];
                mx = fmaxf(mx, fabsf(v[j]));
            }
#pragma unroll
            for (int off = 1; off < 64; off <<= 1) mx = fmaxf(mx, __shfl_xor(mx, off, 64));
            float qs = 127.f / mx;
            unsigned qw = 0;
#pragma unroll
            for (int j = 0; j < 4; ++j) {
                unsigned b = __builtin_bit_cast(unsigned, fmaf(v[j], qs, QMAGIC)) & 255u;
                qw |= b << (8 * j);
            }
            *(unsigned*)(Ut8 + (size_t)i * 256 + lane * 4) = qw;
            if (lane == 0) {
                float sg = (u & 1) ? SCALE_H : SCALE_Z;
                uscl[i] = sg * mx * (1.f / (127.f * 127.f));
            }
        }
    }
    for (int i = tid; i < 2 * 512 * 128; i += nthr) {
        int dir = i >> 16, cc2 = (i >> 7) & 511, k = i & 127;
        const float* W = dir ? ((cc2 & 256) ? Whb : Wzb) : ((cc2 & 256) ? Whf : Wzf);
        Wt[i] = (f16)W[k * 256 + (cc2 & 255)];
    }
    for (int i = tid; i < 512 * 512; i += nthr) {
        int n = i >> 9, k = i & 511;
        W1t[i] = (f16)W1[k * 512 + n];
    }
}

// ---------------------------------------------------------------------------
// K1: input projections, LDS-free. One block = one (dir, g, s). Writes xp2 in
// K2's exact per-thread read layout; epilogue folds the exp2 scale.
// ---------------------------------------------------------------------------
__launch_bounds__(256, 2)
__global__ void k1_xproj(const float* __restrict__ x, const f16* __restrict__ Wt,
                         const float* __restrict__ bzf, const float* __restrict__ bhf,
                         const float* __restrict__ bzb, const float* __restrict__ bhb,
                         f16* __restrict__ xp2)
{
    int bid = blockIdx.x;
    int s = bid & 1023, g = (bid >> 10) & 3, dir = bid >> 12;
    int s_src = dir ? (1023 - s) : s;
    int tid = threadIdx.x, w = tid >> 6, lane = tid & 63, q = lane >> 4, l16 = lane & 15;

    f16x8 bf[4];
    const float* xr = x + ((size_t)(g * 16 + l16) * 1024 + s_src) * 128;
#pragma unroll
    for (int kt = 0; kt < 4; ++kt) {
        int k0 = kt * 32 + q * 8;
        f32x4 a = *(const f32x4*)(xr + k0);
        f32x4 c = *(const f32x4*)(xr + k0 + 4);
        f16x8 v;
#pragma unroll
        for (int j = 0; j < 4; ++j) { v[j] = (f16)a[j]; v[4 + j] = (f16)c[j]; }
        bf[kt] = v;
    }
    const f16* wt = Wt + (size_t)dir * 512 * 128;
    f16x8 af[8][4];
#pragma unroll
    for (int mt = 0; mt < 8; ++mt) {
        int cc2 = w * 128 + mt * 16 + l16;
#pragma unroll
        for (int kt = 0; kt < 4; ++kt)
            af[mt][kt] = *(const f16x8*)(wt + cc2 * 128 + kt * 32 + q * 8);
    }
    f32x4 acc[8];
#pragma unroll
    for (int mt = 0; mt < 8; ++mt) acc[mt] = (f32x4){0.f, 0.f, 0.f, 0.f};
#pragma unroll
    for (int kt = 0; kt < 4; ++kt)
#pragma unroll
        for (int mt = 0; mt < 8; ++mt)
            acc[mt] = MFMA16(af[mt][kt], bf[kt], acc[mt]);

    f16* dst = xp2 + (size_t)((dir * 4 + g) * 1024 + s) * 8192;
#pragma unroll
    for (int mt = 0; mt < 8; ++mt) {
        int ccg = w * 128 + mt * 16 + q * 4;
        int gate = ccg >> 8, c = ccg & 255;
        const float* bias = gate ? (dir ? bhb : bhf) : (dir ? bzb : bzf);
        float sg = gate ? SCALE_H : SCALE_Z;
        f32x4 bi = *(const f32x4*)(bias + c);
        f16x4 o;
#pragma unroll
        for (int r = 0; r < 4; ++r) o[r] = (f16)((acc[mt][r] + bi[r]) * sg);
        int flat = ((gate * 2 + ((c >> 4) & 1)) * 8 + (c >> 5)) * 256 + (q * 16 + l16) * 4;
        *(f16x4*)(dst + flat) = o;
    }
}

// ---------------------------------------------------------------------------
// K2: sequential recurrence — proven R2 single-barrier skeleton, with the
// U-matmul moved to i8 MFMA (16x16x64, 2x the f16 FLOP rate):
//   - MFMA issue per step per SIMD: 1024 -> 512 cyc (the dominant serial
//     chain segment). ds_reads per wave: 8xb128 -> 4xb128.
//   - h kept f32 in registers across steps (full precision recurrence);
//     only the matmul INPUT h is quantized to i8 (|h|<1 strictly -> static
//     scale 127, magic-constant RNE round, 4-byte pack per ds_write_b32).
//   - U rows quantized per-(gate,cc) with scale folded into one epilogue
//     fma: az' = (float)iacc * fs[cc] + cx  (cx carries bias + log2e scales).
//   - A/B both packed with the same (q, byte) k-slot map, so the
//     contraction is exact under relabeling (same map the f16 path used).
// Gate math: independent per element (R6 showed chain-coupling adds stall).
// Raw s_barrier + lgkmcnt(0) only; depth-2 xp2 prefetch (cxA/cxB parity).
// ---------------------------------------------------------------------------
#define GRU_STEP(P, SS, CX)                                                   \
    {                                                                         \
        const int cur = (P), nxt = (P) ^ 1;                                   \
        i32x4 bh[4];                                                          \
        _Pragma("unroll")                                                     \
        for (int j = 0; j < 4; ++j)                                           \
            bh[j] = *(const i32x4*)&h8[cur][l16][j * 64 + q * 16];            \
        i32x4 ia[4];                                                          \
        _Pragma("unroll")                                                     \
        for (int t = 0; t < 4; ++t) ia[t] = (i32x4){0, 0, 0, 0};              \
        int sp = (SS) + 2; if (sp > 1023) sp = 1023;                          \
        const f16* px = xb + (size_t)sp * 8192;                               \
        f16x4 nx[4];                                                          \
        _Pragma("unroll")                                                     \
        for (int t = 0; t < 4; ++t) nx[t] = *(const f16x4*)(px + offs[t]);    \
        _Pragma("unroll")                                                     \
        for (int j = 0; j < 4; ++j)                                           \
            _Pragma("unroll")                                                 \
            for (int t = 0; t < 4; ++t)                                       \
                ia[t] = MFMAI8(uf8[t][j], bh[j], ia[t]);                      \
        _Pragma("unroll")                                                     \
        for (int p = 0; p < 2; ++p) {                                         \
            f32x4 hn; f16x4 hh; unsigned qw = 0;                              \
            _Pragma("unroll")                                                 \
            for (int r = 0; r < 4; ++r) {                                     \
                float az = fmaf((float)ia[p][r], fs4[p][r], (float)CX[p][r]); \
                float ah = fmaf((float)ia[2 + p][r], fs4[2 + p][r],           \
                                (float)CX[2 + p][r]);                         \
                float E1 = fexp2(-az);                                        \
                float E2 = fexp2(-ah);                                        \
                float h0 = hold[p][r];                                        \
                float num = __builtin_fmaf(h0, E2, h0)                        \
                          + __builtin_fmaf(-E1, E2, E1);                      \
                float den = (1.f + E1) * (1.f + E2);                          \
                float hv = num * __builtin_amdgcn_rcpf(den);                  \
                hn[r] = hv; hh[r] = (f16)hv;                                  \
                unsigned qb = __builtin_bit_cast(                             \
                    unsigned, fmaf(hv, 127.f, QMAGIC)) & 255u;                \
                qw |= qb << (8 * r);                                          \
            }                                                                 \
            hold[p] = hn;                                                     \
            *(unsigned*)&h8[nxt][l16][ccg0 + p * 16] = qw;                    \
            *(f16x4*)(op + p * 16) = hh;                                      \
        }                                                                     \
        op += sstep;                                                          \
        _Pragma("unroll")                                                     \
        for (int t = 0; t < 4; ++t) CX[t] = nx[t];                            \
        asm volatile("s_waitcnt lgkmcnt(0)" ::: "memory");                    \
        __builtin_amdgcn_s_barrier();                                         \
        asm volatile("" ::: "memory");                                        \
    }

__launch_bounds__(512, 2)
__global__ void k2_gru(const char* __restrict__ Ut8, const float* __restrict__ uscl,
                       const f16* __restrict__ xp2, f16* __restrict__ out16)
{
    int bid = blockIdx.x;
    int dir = bid >> 2, g = bid & 3;
    int tid = threadIdx.x, w = tid >> 6, lane = tid & 63, q = lane >> 4, l16 = lane & 15;

    __shared__ __align__(16) char h8[2][16][272];   // double-buffered i8 h

    for (int i = tid; i < 2 * 16 * 272 / 4; i += 512) ((int*)h8)[i] = 0;

    // resident i8 U fragments (16 VGPRs). volatile: forbids rematerialization
    // inside the loop -> values stay resident (unified VGPR/AGPR file).
    i32x4 uf8[4][4];
#pragma unroll
    for (int t = 0; t < 4; ++t) {
        int gate = t >> 1;
        int cc = w * 32 + (t & 1) * 16 + l16;
        const char* up = Ut8 + ((size_t)(dir * 2 + gate) * 256 + cc) * 256;
#pragma unroll
        for (int j = 0; j < 4; ++j)
            uf8[t][j] = *(const volatile i32x4*)(up + j * 64 + q * 16);
    }
    // per-thread dequant scales: cc = w*32 + (t&1)*16 + q*4 + r
    f32x4 fs4[4];
#pragma unroll
    for (int t = 0; t < 4; ++t) {
        const float* sp = uscl + (dir * 2 + (t >> 1)) * 256
                        + w * 32 + (t & 1) * 16 + q * 4;
        fs4[t] = *(const f32x4*)sp;
    }

    const f16* xb = xp2 + (size_t)(dir * 4 + g) * 1024 * 8192;
    int offs[4];
#pragma unroll
    for (int t = 0; t < 4; ++t) {
        int gate = t >> 1, p = t & 1;
        offs[t] = ((gate * 2 + p) * 8 + w) * 256 + lane * 4;
    }
    // depth-2 prefetch: cxA = even steps, cxB = odd steps
    f16x4 cxA[4], cxB[4];
#pragma unroll
    for (int t = 0; t < 4; ++t) cxA[t] = *(const f16x4*)(xb + offs[t]);
#pragma unroll
    for (int t = 0; t < 4; ++t) cxB[t] = *(const f16x4*)(xb + 8192 + offs[t]);

    f32x4 hold[2];
    hold[0] = (f32x4){0.f, 0.f, 0.f, 0.f};
    hold[1] = (f32x4){0.f, 0.f, 0.f, 0.f};

    // direct per-thread output pointer: row b = g*16+l16, col = dir*256+w*32+q*4
    f16* op = out16 + ((size_t)(g * 16 + l16) * 1024 + (dir ? 1023 : 0)) * 512
            + dir * 256 + w * 32 + q * 4;
    ptrdiff_t sstep = dir ? -512 : 512;
    int ccg0 = w * 32 + q * 4;

    __syncthreads();   // h8 zero-init visible (once; full drain fine here)

    for (int s = 0; s < 1024; s += 2) {
        GRU_STEP(0, s, cxA)
        GRU_STEP(1, s + 1, cxB)
    }
}

// ---------------------------------------------------------------------------
// K3a: scores = tanh(out @ W1 + b1) @ w2 + b2.
// ---------------------------------------------------------------------------
__launch_bounds__(256, 2)
__global__ void k3_scores(const f16* __restrict__ out16, const f16* __restrict__ W1t,
                          const float* __restrict__ b1, const float* __restrict__ w2,
                          const float* __restrict__ b2, float* __restrict__ scores)
{
    int bid = blockIdx.x;
    int b = bid >> 4, sc = bid & 15, s0 = sc * 64;
    int tid = threadIdx.x, w = tid >> 6, lane = tid & 63, q = lane >> 4, l16 = lane & 15;
    f32x4 acc[4][8];
#pragma unroll
    for (int mt = 0; mt < 4; ++mt)
#pragma unroll
        for (int nt = 0; nt < 8; ++nt) acc[mt][nt] = (f32x4){0.f, 0.f, 0.f, 0.f};

    for (int kt = 0; kt < 16; ++kt) {
        f16x8 af[4];
#pragma unroll
        for (int mt = 0; mt < 4; ++mt) {
            size_t row = (size_t)b * 1024 + s0 + mt * 16 + l16;
            af[mt] = *(const f16x8*)(out16 + row * 512 + kt * 32 + q * 8);
        }
        f16x8 bfg[8];
#pragma unroll
        for (int nt = 0; nt < 8; ++nt) {
            int ncol = w * 128 + nt * 16 + l16;
            bfg[nt] = *(const f16x8*)(W1t + (size_t)ncol * 512 + kt * 32 + q * 8);
        }
#pragma unroll
        for (int mt = 0; mt < 4; ++mt)
#pragma unroll
            for (int nt = 0; nt < 8; ++nt)
                acc[mt][nt] = MFMA16(af[mt], bfg[nt], acc[mt][nt]);
    }
    float b1v[8], w2v[8];
#pragma unroll
    for (int nt = 0; nt < 8; ++nt) {
        int ncol = w * 128 + nt * 16 + l16;
        b1v[nt] = b1[ncol];
        w2v[nt] = w2[ncol];
    }
    __shared__ float spart[4][64];
    float rs[4][4];
#pragma unroll
    for (int mt = 0; mt < 4; ++mt)
#pragma unroll
        for (int r = 0; r < 4; ++r) {
            float ssum = 0.f;
#pragma unroll
            for (int nt = 0; nt < 8; ++nt) {
                float xv = acc[mt][nt][r] + b1v[nt];
                float t = 1.f - 2.f / (1.f + __expf(2.f * xv));
                ssum += t * w2v[nt];
            }
            rs[mt][r] = ssum;
        }
#pragma unroll
    for (int off = 1; off < 16; off <<= 1)
#pragma unroll
        for (int mt = 0; mt < 4; ++mt)
#pragma unroll
            for (int r = 0; r < 4; ++r)
                rs[mt][r] += __shfl_xor(rs[mt][r], off, 64);
    if (l16 == 0) {
#pragma unroll
        for (int mt = 0; mt < 4; ++mt)
#pragma unroll
            for (int r = 0; r < 4; ++r)
                spart[w][mt * 16 + q * 4 + r] = rs[mt][r];
    }
    __syncthreads();
    if (tid < 64) {
        float v = spart[0][tid] + spart[1][tid] + spart[2][tid] + spart[3][tid] + b2[0];
        scores[b * 1024 + s0 + tid] = v;
    }
}

// K3b1: softmax over time per batch.
__global__ void k3_softmax(const float* __restrict__ scores, float* __restrict__ attn)
{
    int b = blockIdx.x, tid = threadIdx.x;
    __shared__ float red[4];
    f32x4 v = *(const f32x4*)(scores + b * 1024 + tid * 4);
    float m = fmaxf(fmaxf(v[0], v[1]), fmaxf(v[2], v[3]));
#pragma unroll
    for (int off = 1; off < 64; off <<= 1) m = fmaxf(m, __shfl_xor(m, off, 64));
    if ((tid & 63) == 0) red[tid >> 6] = m;
    __syncthreads();
    m = fmaxf(fmaxf(red[0], red[1]), fmaxf(red[2], red[3]));
    __syncthreads();
    float e0 = __expf(v[0] - m), e1 = __expf(v[1] - m), e2 = __expf(v[2] - m), e3 = __expf(v[3] - m);
    float ssum = e0 + e1 + e2 + e3;
#pragma unroll
    for (int off = 1; off < 64; off <<= 1) ssum += __shfl_xor(ssum, off, 64);
    if ((tid & 63) == 0) red[tid >> 6] = ssum;
    __syncthreads();
    float inv = 1.f / (red[0] + red[1] + red[2] + red[3]);
    f32x4 o = {e0 * inv, e1 * inv, e2 * inv, e3 * inv};
    *(f32x4*)(attn + b * 1024 + tid * 4) = o;
}

// K3b2: partial weighted sums over s-chunks of 128.
__global__ void k3_wsum(const f16* __restrict__ out16, const float* __restrict__ attn,
                        float* __restrict__ part)
{
    int bid = blockIdx.x;
    int b = bid >> 3, ch = bid & 7;
    int tid = threadIdx.x;
    const f16* op = out16 + ((size_t)b * 1024 + ch * 128) * 512 + tid * 2;
    const float* ap = attn + b * 1024 + ch * 128;
    float a0 = 0.f, a1 = 0.f;
#pragma unroll 4
    for (int i = 0; i < 128; ++i) {
        float aw = ap[i];
        f16x2 xv = *(const f16x2*)(op + (size_t)i * 512);
        a0 += aw * (float)xv[0];
        a1 += aw * (float)xv[1];
    }
    part[(size_t)(b * 8 + ch) * 512 + tid * 2] = a0;
    part[(size_t)(b * 8 + ch) * 512 + tid * 2 + 1] = a1;
}

// K3b3: reduce 8 partials -> context (fp32 output).
__global__ void k3_final(const float* __restrict__ part, float* __restrict__ outp)
{
    int b = blockIdx.x, tid = threadIdx.x;
#pragma unroll
    for (int j = 0; j < 2; ++j) {
        int cc = tid * 2 + j;
        float ssum = 0.f;
#pragma unroll
        for (int ch = 0; ch < 8; ++ch) ssum += part[(size_t)(b * 8 + ch) * 512 + cc];
        outp[b * 512 + cc] = ssum;
    }
}

extern "C" void kernel_launch(void* const* d_in, const int* in_sizes, int n_in,
                              void* d_out, int out_size, void* d_ws, size_t ws_size,
                              hipStream_t stream)
{
    const float* x   = (const float*)d_in[0];
    const float* Wzf = (const float*)d_in[1];
    const float* Uzf = (const float*)d_in[2];
    const float* bzf = (const float*)d_in[3];
    const float* Whf = (const float*)d_in[4];
    const float* Uhf = (const float*)d_in[5];
    const float* bhf = (const float*)d_in[6];
    const float* Wzb = (const float*)d_in[7];
    const float* Uzb = (const float*)d_in[8];
    const float* bzb = (const float*)d_in[9];
    const float* Whb = (const float*)d_in[10];
    const float* Uhb = (const float*)d_in[11];
    const float* bhb = (const float*)d_in[12];
    const float* W1  = (const float*)d_in[13];
    const float* b1  = (const float*)d_in[14];
    const float* w2  = (const float*)d_in[15];
    const float* b2  = (const float*)d_in[16];
    float* outp = (float*)d_out;

    char* ws = (char*)d_ws;
    char* Ut8  = ws + UT8_OFF;
    float* usc = (float*)(ws + USCL_OFF);
    f16* Wt    = (f16*)(ws + WT_OFF);
    f16* W1t   = (f16*)(ws + W1T_OFF);
    f16* xp2   = (f16*)(ws + XP_OFF);
    f16* o16   = (f16*)(ws + OUT_OFF);
    float* sc  = (float*)(ws + SC_OFF);
    float* at  = (float*)(ws + AT_OFF);
    float* pt  = (float*)(ws + PART_OFF);

    hipLaunchKernelGGL(k0_prep, dim3(256), dim3(256), 0, stream,
                       Uzf, Uhf, Uzb, Uhb, Wzf, Whf, Wzb, Whb, W1, Ut8, usc, Wt, W1t);
    hipLaunchKernelGGL(k1_xproj, dim3(8192), dim3(256), 0, stream,
                       x, Wt, bzf, bhf, bzb, bhb, xp2);
    hipLaunchKernelGGL(k2_gru, dim3(8), dim3(512), 0, stream, Ut8, usc, xp2, o16);
    hipLaunchKernelGGL(k3_scores, dim3(1024), dim3(256), 0, stream, o16, W1t, b1, w2, b2, sc);
    hipLaunchKernelGGL(k3_softmax, dim3(64), dim3(256), 0, stream, sc, at);
    hipLaunchKernelGGL(k3_wsum, dim3(512), dim3(256), 0, stream, o16, at, pt);
    hipLaunchKernelGGL(k3_final, dim3(64), dim3(256), 0, stream, pt, outp);
}